// Round 7
// baseline (588.631 us; speedup 1.0000x reference)
//
#include <hip/hip_runtime.h>
#include <cstdint>
#include <cstddef>

// Problem constants
#define NB 2
#define NT 8192
#define ND 1024
#define NH 4
#define NQK 512
#define NV 1024
#define NHK 128
#define NHV 256
#define CHK 64
#define NCHK 128            // chunks per (b,h)
#define SCALE 0.08838834764831845f   // HK^-0.5

using f32x4 = __attribute__((ext_vector_type(4))) float;
using short8 = __attribute__((ext_vector_type(8))) short;
using s16x4 = __attribute__((ext_vector_type(4))) short;

__device__ __forceinline__ float bf2f(unsigned short u){
  union { unsigned int i; float f; } t; t.i = ((unsigned int)u) << 16; return t.f;
}
__device__ __forceinline__ unsigned short f2bf(float f){
  union { float f; unsigned int i; } t; t.f = f;
  unsigned int r = t.i + 0x7fffu + ((t.i >> 16) & 1u);
  return (unsigned short)(r >> 16);
}
__device__ __forceinline__ double shfl_up_dbl(double v, int off){
  union { double d; unsigned int u[2]; } a, r;
  a.d = v;
  r.u[0] = __shfl_up(a.u[0], off, 64);
  r.u[1] = __shfl_up(a.u[1], off, 64);
  return r.d;
}
// Swizzled LDS accessor for bf16 tiles: row-major, rowBytes in {128,256}.
__device__ __forceinline__ void* lds_at(void* base, int row, int colElem, int rowBytes){
  return (void*)((char*)base + row*rowBytes + (((colElem*2) ^ ((row&7)<<4))));
}

// ---------------- weight transpose+cast (single): dst[c][r] = bf16(src[r][c]) ----------------
__global__ __launch_bounds__(256) void k_tc(const float* __restrict__ src,
                                            unsigned short* __restrict__ dst, int R, int C){
  int idx = blockIdx.x*256 + threadIdx.x;
  if (idx >= R*C) return;
  int r = idx % R, c = idx / R;
  dst[(size_t)c*R + r] = f2bf(src[(size_t)r*C + c]);
}

// ---------------- weight transpose+cast hi/lo pair ----------------
__global__ __launch_bounds__(256) void k_tc2(const float* __restrict__ src,
                                             unsigned short* __restrict__ dh,
                                             unsigned short* __restrict__ dl, int R, int C){
  int idx = blockIdx.x*256 + threadIdx.x;
  if (idx >= R*C) return;
  int r = idx % R, c = idx / R;
  float x = src[(size_t)r*C + c];
  unsigned short h = f2bf(x);
  unsigned short l = f2bf(x - bf2f(h));
  dh[(size_t)c*R + r] = h;
  dl[(size_t)c*R + r] = l;
}

// ---------------- split fp32 -> (hi,lo) bf16, 8 elems/thread ----------------
__global__ __launch_bounds__(256) void k_split(const float* __restrict__ s,
                                               unsigned short* __restrict__ dh,
                                               unsigned short* __restrict__ dl, int n){
  int i = (blockIdx.x*256 + threadIdx.x)*8;
  if (i >= n) return;
  f32x4 x0 = *(const f32x4*)(s+i);
  f32x4 x1 = *(const f32x4*)(s+i+4);
  short8 h8, l8;
  #pragma unroll
  for (int e=0;e<4;e++){
    unsigned short h0 = f2bf(x0[e]); h8[e]   = (short)h0; l8[e]   = (short)f2bf(x0[e] - bf2f(h0));
    unsigned short h1 = f2bf(x1[e]); h8[e+4] = (short)h1; l8[e+4] = (short)f2bf(x1[e] - bf2f(h1));
  }
  *(short8*)(dh+i) = h8;
  *(short8*)(dl+i) = l8;
}

// ------- split GEMM: C = (Ah+Al)[M][K] @ Bt^T (+ Ah@Bl^T if BSPLIT), all bf16 staged -------
template<int BSPLIT>
__global__ __launch_bounds__(256) void k_gemm2(const unsigned short* __restrict__ A2h,
                                               const unsigned short* __restrict__ A2l,
                                               const unsigned short* __restrict__ Bth,
                                               const unsigned short* __restrict__ Btl,
                                               unsigned short* __restrict__ C, int M, int N, int K){
  __shared__ unsigned short Ah[128][40];
  __shared__ unsigned short Al[128][40];
  __shared__ unsigned short Bh[128][40];
  __shared__ unsigned short Bl[128][40];
  int tid = threadIdx.x, lane = tid & 63, wave = tid >> 6;
  int m0 = blockIdx.x*128, n0 = blockIdx.y*128;
  int wr = (wave>>1)*64, wc = (wave&1)*64;
  int row = lane & 15, kq = (lane>>4)*8;
  f32x4 acc[4][4];
  #pragma unroll
  for (int m=0;m<4;m++)
    #pragma unroll
    for (int n=0;n<4;n++)
      #pragma unroll
      for (int r=0;r<4;r++) acc[m][n][r] = 0.f;

  for (int k0=0;k0<K;k0+=32){
    __syncthreads();
    #pragma unroll
    for (int it=0; it<2; ++it){
      int s = tid + it*256;
      int r = s>>2, cb = (s&3)*8;
      *(f32x4*)(&Ah[r][cb]) = *(const f32x4*)(A2h + (size_t)(m0+r)*K + k0 + cb);
      *(f32x4*)(&Al[r][cb]) = *(const f32x4*)(A2l + (size_t)(m0+r)*K + k0 + cb);
      *(f32x4*)(&Bh[r][cb]) = *(const f32x4*)(Bth + (size_t)(n0+r)*K + k0 + cb);
      if (BSPLIT)
        *(f32x4*)(&Bl[r][cb]) = *(const f32x4*)(Btl + (size_t)(n0+r)*K + k0 + cb);
    }
    __syncthreads();
    short8 ah[4], al[4], bh[4];
    #pragma unroll
    for (int m=0;m<4;m++){ ah[m] = *(const short8*)(&Ah[wr + m*16 + row][kq]);
                           al[m] = *(const short8*)(&Al[wr + m*16 + row][kq]); }
    #pragma unroll
    for (int n=0;n<4;n++) bh[n] = *(const short8*)(&Bh[wc + n*16 + row][kq]);
    #pragma unroll
    for (int m=0;m<4;m++)
      #pragma unroll
      for (int n=0;n<4;n++){
        acc[m][n] = __builtin_amdgcn_mfma_f32_16x16x32_bf16(ah[m], bh[n], acc[m][n], 0, 0, 0);
        acc[m][n] = __builtin_amdgcn_mfma_f32_16x16x32_bf16(al[m], bh[n], acc[m][n], 0, 0, 0);
      }
    if (BSPLIT){
      short8 bl[4];
      #pragma unroll
      for (int n=0;n<4;n++) bl[n] = *(const short8*)(&Bl[wc + n*16 + row][kq]);
      #pragma unroll
      for (int m=0;m<4;m++)
        #pragma unroll
        for (int n=0;n<4;n++)
          acc[m][n] = __builtin_amdgcn_mfma_f32_16x16x32_bf16(ah[m], bl[n], acc[m][n], 0, 0, 0);
    }
  }
  #pragma unroll
  for (int m=0;m<4;m++)
    #pragma unroll
    for (int n=0;n<4;n++)
      #pragma unroll
      for (int r=0;r<4;r++){
        int rr = m0 + wr + m*16 + (lane>>4)*4 + r;
        int cc = n0 + wc + n*16 + (lane&15);
        C[(size_t)rr*N + cc] = f2bf(acc[m][n][r]);
      }
}

// ---------------- plain bf16 GEMM (final projection, fp32 out) ----------------
__global__ __launch_bounds__(256) void k_gemm(const unsigned short* __restrict__ A,
                                              const unsigned short* __restrict__ Bt,
                                              float* __restrict__ C, int M, int N, int K){
  __shared__ unsigned short As[128][40];
  __shared__ unsigned short Bs[128][40];
  int tid = threadIdx.x, lane = tid & 63, wave = tid >> 6;
  int m0 = blockIdx.x*128, n0 = blockIdx.y*128;
  int wr = (wave>>1)*64, wc = (wave&1)*64;
  int row = lane & 15, kq = (lane>>4)*8;
  f32x4 acc[4][4];
  #pragma unroll
  for (int m=0;m<4;m++)
    #pragma unroll
    for (int n=0;n<4;n++)
      #pragma unroll
      for (int r=0;r<4;r++) acc[m][n][r] = 0.f;

  for (int k0=0;k0<K;k0+=32){
    __syncthreads();
    #pragma unroll
    for (int it=0; it<2; ++it){
      int s = tid + it*256;
      int r = s>>2, cb = (s&3)*8;
      *(f32x4*)(&As[r][cb]) = *(const f32x4*)(A  + (size_t)(m0+r)*K + k0 + cb);
      *(f32x4*)(&Bs[r][cb]) = *(const f32x4*)(Bt + (size_t)(n0+r)*K + k0 + cb);
    }
    __syncthreads();
    short8 af[4], bfr[4];
    #pragma unroll
    for (int m=0;m<4;m++) af[m]  = *(const short8*)(&As[wr + m*16 + row][kq]);
    #pragma unroll
    for (int n=0;n<4;n++) bfr[n] = *(const short8*)(&Bs[wc + n*16 + row][kq]);
    #pragma unroll
    for (int m=0;m<4;m++)
      #pragma unroll
      for (int n=0;n<4;n++)
        acc[m][n] = __builtin_amdgcn_mfma_f32_16x16x32_bf16(af[m], bfr[n], acc[m][n], 0, 0, 0);
  }
  #pragma unroll
  for (int m=0;m<4;m++)
    #pragma unroll
    for (int n=0;n<4;n++)
      #pragma unroll
      for (int r=0;r<4;r++){
        int rr = m0 + wr + m*16 + (lane>>4)*4 + r;
        int cc = n0 + wc + n*16 + (lane&15);
        C[(size_t)rr*N + cc] = acc[m][n][r];
      }
}

// ---------------- exact fp32 alpha -> gk (pre-cumsum), layout G[(b*H+h)*T + t] ----------------
__global__ __launch_bounds__(256) void k_alpha(const float* __restrict__ hs, const float* __restrict__ Wa,
                                               const float* __restrict__ Al, const float* __restrict__ dtb,
                                               float* __restrict__ Gc){
  int rowi = blockIdx.x;
  int tid = threadIdx.x;
  const float* h = hs + (size_t)rowi*ND;
  float a0=0.f,a1=0.f,a2=0.f,a3=0.f;
  for (int d=tid; d<ND; d+=256){
    float x = h[d];
    a0 += x*Wa[d*4+0]; a1 += x*Wa[d*4+1]; a2 += x*Wa[d*4+2]; a3 += x*Wa[d*4+3];
  }
  #pragma unroll
  for (int off=32; off>0; off>>=1){
    a0 += __shfl_down(a0, off, 64); a1 += __shfl_down(a1, off, 64);
    a2 += __shfl_down(a2, off, 64); a3 += __shfl_down(a3, off, 64);
  }
  __shared__ float red[4][4];
  if ((tid&63)==0){ int w = tid>>6; red[w][0]=a0; red[w][1]=a1; red[w][2]=a2; red[w][3]=a3; }
  __syncthreads();
  if (tid < 4){
    float al = red[0][tid]+red[1][tid]+red[2][tid]+red[3][tid];
    float x = al + dtb[tid];
    float sp = (x > 20.f) ? x : log1pf(expf(x));
    float gkv = -expf(Al[tid]) * sp;
    int bb = rowi >> 13, t = rowi & (NT-1);
    Gc[((size_t)(bb*NH + tid))*NT + t] = gkv;
  }
}

// ---------------- inclusive cumsum over t in DOUBLE: Gd[bh][t] ----------------
__global__ __launch_bounds__(256) void k_cumsum(const float* __restrict__ Gc, double* __restrict__ Gd){
  int bh = blockIdx.x, tid = threadIdx.x;
  const float* g = Gc + (size_t)bh*NT;
  double* out = Gd + (size_t)bh*NT;
  __shared__ double wsum[4];
  __shared__ double carry_s;
  if (tid==0) carry_s = 0.0;
  __syncthreads();
  for (int t0=0; t0<NT; t0+=256){
    double v = (double)g[t0+tid];
    #pragma unroll
    for (int off=1; off<64; off<<=1){
      double y = shfl_up_dbl(v, off);
      if ((tid&63) >= off) v += y;
    }
    if ((tid&63)==63) wsum[tid>>6] = v;
    __syncthreads();
    double add = carry_s;
    for (int w=0; w<(tid>>6); ++w) add += wsum[w];
    v += add;
    out[t0+tid] = v;
    __syncthreads();
    if (tid==255) carry_s = v;
    __syncthreads();
  }
}

// ---- phase A (MFMA, per-chunk): S_loc^T[n][k] = sum_j exp(Gend-Gj) v_j k_j, bf16 out ----
__global__ __launch_bounds__(256) void k_phaseA(const unsigned short* __restrict__ kb,
                                                const unsigned short* __restrict__ vb,
                                                const double* __restrict__ Gd,
                                                unsigned short* __restrict__ Sbc){
  __shared__ unsigned short vT[16384];   // [256 n][64 j] swizzled
  __shared__ unsigned short wkT[8192];   // [128 k][64 j] swizzled
  int blk = blockIdx.x, bh = blockIdx.y;   // chunk, bh
  int bb = bh>>2, hh = bh&3;
  int cs = blk*CHK, tid = threadIdx.x;
  int lane = tid & 63, w = tid >> 6;
  const double* Gb = Gd + (size_t)bh*NT;
  double Gend = Gb[cs + 63];
  #pragma unroll
  for (int it=0; it<8; ++it){
    int task = it*256 + tid;
    int j = task & 63, ng = task >> 6;
    short8 vv = *(const short8*)(vb + (size_t)(bb*NT + cs + j)*NV + hh*NHV + ng*8);
    #pragma unroll
    for (int e=0;e<8;e++)
      *(unsigned short*)lds_at(vT, ng*8+e, j, 128) = (unsigned short)vv[e];
  }
  #pragma unroll
  for (int it=0; it<4; ++it){
    int task = it*256 + tid;
    int j = task & 63, kg = task >> 6;
    float wj = expf((float)(Gend - Gb[cs + j]));
    short8 kv = *(const short8*)(kb + (size_t)(bb*NT + cs + j)*NQK + hh*NHK + kg*8);
    #pragma unroll
    for (int e=0;e<8;e++)
      *(unsigned short*)lds_at(wkT, kg*8+e, j, 128) = f2bf(wj * bf2f((unsigned short)kv[e]));
  }
  __syncthreads();
  f32x4 sa[32];
  #pragma unroll
  for (int i=0;i<32;i++) sa[i] = (f32x4){0.f,0.f,0.f,0.f};
  short8 wa[2][2];
  #pragma unroll
  for (int mt=0;mt<2;mt++)
    #pragma unroll
    for (int kk=0;kk<2;kk++)
      wa[mt][kk] = *(short8*)lds_at(wkT, 32*w + mt*16 + (lane&15), kk*32 + (lane>>4)*8, 128);
  #pragma unroll
  for (int mt=0;mt<2;mt++)
    #pragma unroll
    for (int nt=0;nt<16;nt++)
      #pragma unroll
      for (int kk=0;kk<2;kk++){
        short8 b = *(short8*)lds_at(vT, nt*16 + (lane&15), kk*32 + (lane>>4)*8, 128);
        sa[mt*16+nt] = __builtin_amdgcn_mfma_f32_16x16x32_bf16(wa[mt][kk], b, sa[mt*16+nt], 0,0,0);
      }
  // write bf16 state [n][k]
  unsigned short* dst = Sbc + (size_t)(bh*NCHK + blk)*32768;
  #pragma unroll
  for (int mt=0;mt<2;mt++)
    #pragma unroll
    for (int nt=0;nt<16;nt++){
      int k = 32*w + mt*16 + (lane>>4)*4;
      int n = nt*16 + (lane&15);
      s16x4 p;
      #pragma unroll
      for (int r=0;r<4;r++) p[r] = (short)f2bf(sa[mt*16+nt][r]);
      *(s16x4*)(dst + (size_t)n*128 + k) = p;
    }
}

// ---------------- phase B: parallel elementwise scan over chunk states (bf16 io, fp32 run) ----
__global__ __launch_bounds__(256) void k_phaseB(unsigned short* __restrict__ Sbc,
                                                const double* __restrict__ Gd){
  int slice = blockIdx.x, bh = blockIdx.y;
  int tid = threadIdx.x;
  const double* Gb = Gd + (size_t)bh*NT;
  unsigned short* base = Sbc + (size_t)(bh*NCHK)*32768 + slice*1024 + tid*4;
  s16x4 c0 = *(const s16x4*)(base);
  f32x4 run;
  #pragma unroll
  for (int e=0;e<4;e++) run[e] = bf2f((unsigned short)c0[e]);
  s16x4 nxt = *(const s16x4*)(base + 32768);
  for (int b=1; b<NCHK; ++b){
    s16x4 cur = nxt;
    if (b+1 < NCHK) nxt = *(const s16x4*)(base + (size_t)(b+1)*32768);
    float resc = expf((float)(Gb[b*CHK + 63] - Gb[b*CHK - 1]));
    s16x4 outp;
    #pragma unroll
    for (int e=0;e<4;e++){
      run[e] = resc*run[e] + bf2f((unsigned short)cur[e]);
      outp[e] = (short)f2bf(run[e]);
    }
    *(s16x4*)(base + (size_t)b*32768) = outp;
  }
}

// ---- phase C (per-chunk): o = qg @ S^T + maskedP @ V, fused RMSNorm/gate, o2 in-place over g ----
__global__ __launch_bounds__(256) void k_phaseC(const unsigned short* __restrict__ qb,
                                                const unsigned short* __restrict__ kb,
                                                const unsigned short* __restrict__ vb,
                                                unsigned short* __restrict__ gio,
                                                const float* __restrict__ rmsw,
                                                const double* __restrict__ Gd,
                                                const unsigned short* __restrict__ Sbc,
                                                int dummy){
  __shared__ unsigned short vT[16384];   // [256 n][64 j] swizzled
  __shared__ unsigned short scp[4096];   // [64][64] swizzled
  __shared__ float Gsf[64];
  int blk = blockIdx.x, bh = blockIdx.y;   // chunk, bh
  int bb = bh>>2, hh = bh&3;
  int cs = blk*CHK, tid = threadIdx.x;
  int lane = tid&63, w = tid>>6;
  const double* Gb = Gd + (size_t)bh*NT;
  // stage vT + Gsf
  #pragma unroll
  for (int it=0; it<8; ++it){
    int task = it*256 + tid;
    int j = task & 63, ng = task >> 6;
    short8 vv = *(const short8*)(vb + (size_t)(bb*NT + cs + j)*NV + hh*NHV + ng*8);
    #pragma unroll
    for (int e=0;e<8;e++)
      *(unsigned short*)lds_at(vT, ng*8+e, j, 128) = (unsigned short)vv[e];
  }
  if (tid < 64){
    double ref = (cs == 0) ? 0.0 : Gb[cs-1];
    Gsf[tid] = (float)(Gb[cs+tid] - ref);
  }
  __syncthreads();
  int irow = 16*w + (lane&15);
  // q fragments direct from global
  const unsigned short* qrow = qb + (size_t)(bb*NT + cs + irow)*NQK + hh*NHK;
  short8 qaraw[4], qag[4];
  float si = SCALE * expf(Gsf[irow]);
  #pragma unroll
  for (int kk=0;kk<4;kk++){
    short8 a = *(const short8*)(qrow + kk*32 + (lane>>4)*8);
    qaraw[kk] = a;
    short8 g;
    #pragma unroll
    for (int e=0;e<8;e++) g[e] = (short)f2bf(si * bf2f((unsigned short)a[e]));
    qag[kk] = g;
  }
  // P = q @ k^T (k fragments direct from global)
  f32x4 pa[4];
  #pragma unroll
  for (int jt=0;jt<4;jt++) pa[jt] = (f32x4){0.f,0.f,0.f,0.f};
  #pragma unroll
  for (int jt=0;jt<4;jt++)
    #pragma unroll
    for (int kk=0;kk<4;kk++){
      short8 b = *(const short8*)(kb + (size_t)(bb*NT + cs + jt*16 + (lane&15))*NQK
                                  + hh*NHK + kk*32 + (lane>>4)*8);
      pa[jt] = __builtin_amdgcn_mfma_f32_16x16x32_bf16(qaraw[kk], b, pa[jt], 0,0,0);
    }
  // weight + causal mask on fragments -> scp (bf16)
  #pragma unroll
  for (int jt=0;jt<4;jt++)
    #pragma unroll
    for (int r=0;r<4;r++){
      int il = 16*w + (lane>>4)*4 + r;
      int jl = jt*16 + (lane&15);
      float wgt = (jl <= il) ? SCALE * expf(Gsf[il] - Gsf[jl]) : 0.f;
      *(unsigned short*)lds_at(scp, il, jl, 128) = f2bf(wgt * pa[jt][r]);
    }
  // o_inter: S fragments direct from global (state after chunk blk-1)
  f32x4 oa[16];
  #pragma unroll
  for (int nt=0;nt<16;nt++) oa[nt] = (f32x4){0.f,0.f,0.f,0.f};
  if (blk > 0){
    const unsigned short* Sst = Sbc + (size_t)(bh*NCHK + blk - 1)*32768;
    #pragma unroll
    for (int nt=0;nt<16;nt++)
      #pragma unroll
      for (int kk=0;kk<4;kk++){
        short8 b = *(const short8*)(Sst + (size_t)(nt*16 + (lane&15))*128 + kk*32 + (lane>>4)*8);
        oa[nt] = __builtin_amdgcn_mfma_f32_16x16x32_bf16(qag[kk], b, oa[nt], 0,0,0);
      }
  }
  __syncthreads();   // scp written by all waves
  // o += scp @ vT^T (K=64)
  short8 sa2[2];
  #pragma unroll
  for (int kk=0;kk<2;kk++)
    sa2[kk] = *(short8*)lds_at(scp, irow, kk*32 + (lane>>4)*8, 128);
  #pragma unroll
  for (int nt=0;nt<16;nt++)
    #pragma unroll
    for (int kk=0;kk<2;kk++){
      short8 b = *(short8*)lds_at(vT, nt*16 + (lane&15), kk*32 + (lane>>4)*8, 128);
      oa[nt] = __builtin_amdgcn_mfma_f32_16x16x32_bf16(sa2[kk], b, oa[nt], 0,0,0);
    }
  // epilogue: RMSNorm over n (sum over nt in-thread + 16 lanes of lane&15) + swish gate
  float p4[4] = {0.f,0.f,0.f,0.f};
  #pragma unroll
  for (int nt=0;nt<16;nt++)
    #pragma unroll
    for (int r=0;r<4;r++) p4[r] += oa[nt][r]*oa[nt][r];
  #pragma unroll
  for (int r=0;r<4;r++){
    #pragma unroll
    for (int off=1; off<16; off<<=1) p4[r] += __shfl_xor(p4[r], off, 16);
  }
  float fr[4];
  #pragma unroll
  for (int r=0;r<4;r++) fr[r] = rsqrtf(p4[r]*(1.f/256.f) + 1e-5f);
  #pragma unroll
  for (int nt=0;nt<16;nt++)
    #pragma unroll
    for (int r=0;r<4;r++){
      int tg = cs + 16*w + (lane>>4)*4 + r;
      int n = nt*16 + (lane&15);
      size_t gidx = (size_t)(bb*NT + tg)*NV + hh*NHV + n;
      float gv = bf2f(gio[gidx]);
      float sw = gv / (1.f + expf(-gv));
      gio[gidx] = f2bf(oa[nt][r] * fr[r] * rmsw[n] * sw);
    }
  (void)dummy;
}

// ---------------- launch ----------------
extern "C" void kernel_launch(void* const* d_in, const int* in_sizes, int n_in,
                              void* d_out, int out_size, void* d_ws, size_t ws_size,
                              hipStream_t stream) {
  (void)in_sizes; (void)n_in; (void)out_size;
  const float* hs  = (const float*)d_in[0];
  const float* Wq  = (const float*)d_in[1];
  const float* Wk  = (const float*)d_in[2];
  const float* Wv  = (const float*)d_in[3];
  const float* Wa  = (const float*)d_in[4];
  const float* Wg  = (const float*)d_in[5];
  const float* Wo  = (const float*)d_in[6];
  const float* Al  = (const float*)d_in[7];
  const float* dtb = (const float*)d_in[8];
  const float* rmsw= (const float*)d_in[9];
  char* ws = (char*)d_ws;

  // workspace layout — total stays within known-safe 176,947,200 B
  constexpr size_t MB = 1048576;
  constexpr size_t OFF_Q    = 0;            // 16MB bf16 q
  constexpr size_t OFF_K    = 16*MB;        // 16MB bf16 k
  constexpr size_t OFF_V    = 32*MB;        // 32MB bf16 v
  constexpr size_t OFF_G    = 64*MB;        // 32MB bf16 gate -> o2 in-place
  constexpr size_t OFF_WQH  = 96*MB;        // 1MB
  constexpr size_t OFF_WQL  = 97*MB;        // 1MB
  constexpr size_t OFF_WKH  = 98*MB;        // 1MB
  constexpr size_t OFF_WKL  = 99*MB;        // 1MB
  constexpr size_t OFF_WV   = 100*MB;       // 2MB
  constexpr size_t OFF_WG   = 102*MB;       // 2MB
  constexpr size_t OFF_WO   = 104*MB;       // 2MB
  constexpr size_t OFF_GC   = 106*MB;                 // 256KB
  constexpr size_t OFF_GD   = 106*MB + 262144;        // 512KB
  constexpr size_t OFF_SBC  = 107*MB;       // 64MB bf16 chunk states; hsh/hsl alias here pre-phaseA
  constexpr size_t WS_REQUIRED = 176947200;
  if (ws_size < WS_REQUIRED) return;

  unsigned short* qb  = (unsigned short*)(ws + OFF_Q);
  unsigned short* kb  = (unsigned short*)(ws + OFF_K);
  unsigned short* vb  = (unsigned short*)(ws + OFF_V);
  unsigned short* gb  = (unsigned short*)(ws + OFF_G);
  unsigned short* wqh = (unsigned short*)(ws + OFF_WQH);
  unsigned short* wql = (unsigned short*)(ws + OFF_WQL);
  unsigned short* wkh = (unsigned short*)(ws + OFF_WKH);
  unsigned short* wkl = (unsigned short*)(ws + OFF_WKL);
  unsigned short* wvt = (unsigned short*)(ws + OFF_WV);
  unsigned short* wgt = (unsigned short*)(ws + OFF_WG);
  unsigned short* wot = (unsigned short*)(ws + OFF_WO);
  float* Gc   = (float*)(ws + OFF_GC);
  double* Gd  = (double*)(ws + OFF_GD);
  unsigned short* Sbc = (unsigned short*)(ws + OFF_SBC);
  unsigned short* hsh = (unsigned short*)(ws + OFF_SBC);          // 32MB, dead before phaseA
  unsigned short* hsl = (unsigned short*)(ws + OFF_SBC + 32*MB);  // 32MB, dead before phaseA

  // hs hi/lo split + weight transposes
  k_split<<<8192, 256, 0, stream>>>(hs, hsh, hsl, NB*NT*ND);
  k_tc2<<<2048, 256, 0, stream>>>(Wq, wqh, wql, 1024, 512);
  k_tc2<<<2048, 256, 0, stream>>>(Wk, wkh, wkl, 1024, 512);
  k_tc <<<4096, 256, 0, stream>>>(Wv, wvt, 1024, 1024);
  k_tc <<<4096, 256, 0, stream>>>(Wg, wgt, 1024, 1024);
  k_tc <<<4096, 256, 0, stream>>>(Wo, wot, 1024, 1024);

  // projections (A = hs_hi + hs_lo, bf16 staged)
  k_gemm2<1><<<dim3(128,4), 256, 0, stream>>>(hsh, hsl, wqh, wql, qb, 16384, 512, 1024);
  k_gemm2<1><<<dim3(128,4), 256, 0, stream>>>(hsh, hsl, wkh, wkl, kb, 16384, 512, 1024);
  k_gemm2<0><<<dim3(128,8), 256, 0, stream>>>(hsh, hsl, wvt, nullptr, vb, 16384, 1024, 1024);
  k_gemm2<0><<<dim3(128,8), 256, 0, stream>>>(hsh, hsl, wgt, nullptr, gb, 16384, 1024, 1024);

  k_alpha<<<16384, 256, 0, stream>>>(hs, Wa, Al, dtb, Gc);
  k_cumsum<<<8, 256, 0, stream>>>(Gc, Gd);

  k_phaseA<<<dim3(NCHK,8), 256, 0, stream>>>(kb, vb, Gd, Sbc);
  k_phaseB<<<dim3(32,8), 256, 0, stream>>>(Sbc, Gd);
  k_phaseC<<<dim3(NCHK,8), 256, 0, stream>>>(qb, kb, vb, gb, rmsw, Gd, Sbc, 0);

  // final GEMM: o2 (= gb region) @ Wo^T
  k_gemm<<<dim3(128,8), 256, 0, stream>>>(gb, wot, (float*)d_out, 16384, 1024, 1024);
}

// Round 8
// 568.508 us; speedup vs baseline: 1.0354x; 1.0354x over previous
//
#include <hip/hip_runtime.h>
#include <cstdint>
#include <cstddef>

// Problem constants
#define NB 2
#define NT 8192
#define ND 1024
#define NH 4
#define NQK 512
#define NV 1024
#define NHK 128
#define NHV 256
#define CHK 64
#define NCHK 128            // chunks per (b,h)
#define SCALE 0.08838834764831845f   // HK^-0.5

using f32x4 = __attribute__((ext_vector_type(4))) float;
using short8 = __attribute__((ext_vector_type(8))) short;
using s16x4 = __attribute__((ext_vector_type(4))) short;

__device__ __forceinline__ float bf2f(unsigned short u){
  union { unsigned int i; float f; } t; t.i = ((unsigned int)u) << 16; return t.f;
}
__device__ __forceinline__ unsigned short f2bf(float f){
  union { float f; unsigned int i; } t; t.f = f;
  unsigned int r = t.i + 0x7fffu + ((t.i >> 16) & 1u);
  return (unsigned short)(r >> 16);
}
__device__ __forceinline__ double shfl_up_dbl(double v, int off){
  union { double d; unsigned int u[2]; } a, r;
  a.d = v;
  r.u[0] = __shfl_up(a.u[0], off, 64);
  r.u[1] = __shfl_up(a.u[1], off, 64);
  return r.d;
}
// Swizzled LDS accessor for bf16 tiles: row-major, rowBytes in {128,256}.
__device__ __forceinline__ void* lds_at(void* base, int row, int colElem, int rowBytes){
  return (void*)((char*)base + row*rowBytes + (((colElem*2) ^ ((row&7)<<4))));
}

// ---- async global->LDS, 16B per lane; dest is wave-uniform base + lane*16 (m97 pattern) ----
typedef const __attribute__((address_space(1))) unsigned int as1_u32;
typedef __attribute__((address_space(3))) unsigned int as3_u32;
__device__ __forceinline__ void gl_lds16(const void* g_lane, void* lds_uniform){
  __builtin_amdgcn_global_load_lds((as1_u32*)(uintptr_t)g_lane,
                                   (as3_u32*)(unsigned int)(uintptr_t)lds_uniform,
                                   16, 0, 0);
}

// ---------------- weight transpose+cast (single): dst[c][r] = bf16(src[r][c]) ----------------
__global__ __launch_bounds__(256) void k_tc(const float* __restrict__ src,
                                            unsigned short* __restrict__ dst, int R, int C){
  int idx = blockIdx.x*256 + threadIdx.x;
  if (idx >= R*C) return;
  int r = idx % R, c = idx / R;
  dst[(size_t)c*R + r] = f2bf(src[(size_t)r*C + c]);
}

// ---------------- weight transpose+cast hi/lo pair ----------------
__global__ __launch_bounds__(256) void k_tc2(const float* __restrict__ src,
                                             unsigned short* __restrict__ dh,
                                             unsigned short* __restrict__ dl, int R, int C){
  int idx = blockIdx.x*256 + threadIdx.x;
  if (idx >= R*C) return;
  int r = idx % R, c = idx / R;
  float x = src[(size_t)r*C + c];
  unsigned short h = f2bf(x);
  unsigned short l = f2bf(x - bf2f(h));
  dh[(size_t)c*R + r] = h;
  dl[(size_t)c*R + r] = l;
}

// ---------------- split fp32 -> (hi,lo) bf16, 8 elems/thread ----------------
__global__ __launch_bounds__(256) void k_split(const float* __restrict__ s,
                                               unsigned short* __restrict__ dh,
                                               unsigned short* __restrict__ dl, int n){
  int i = (blockIdx.x*256 + threadIdx.x)*8;
  if (i >= n) return;
  f32x4 x0 = *(const f32x4*)(s+i);
  f32x4 x1 = *(const f32x4*)(s+i+4);
  short8 h8, l8;
  #pragma unroll
  for (int e=0;e<4;e++){
    unsigned short h0 = f2bf(x0[e]); h8[e]   = (short)h0; l8[e]   = (short)f2bf(x0[e] - bf2f(h0));
    unsigned short h1 = f2bf(x1[e]); h8[e+4] = (short)h1; l8[e+4] = (short)f2bf(x1[e] - bf2f(h1));
  }
  *(short8*)(dh+i) = h8;
  *(short8*)(dl+i) = l8;
}

// ------- split GEMM (global_load_lds staged): C = (Ah+Al) @ Bt^T (+ Ah@Bl^T if BSPLIT) -------
template<int BSPLIT>
__global__ __launch_bounds__(256) void k_gemm2(const unsigned short* __restrict__ A2h,
                                               const unsigned short* __restrict__ A2l,
                                               const unsigned short* __restrict__ Bth,
                                               const unsigned short* __restrict__ Btl,
                                               unsigned short* __restrict__ C, int M, int N, int K){
  // linear [128][32] bf16 buffers (64B rows), contiguous for global_load_lds
  __shared__ unsigned short sAh[4096];
  __shared__ unsigned short sAl[4096];
  __shared__ unsigned short sBh[4096];
  __shared__ unsigned short sBl[4096];
  int tid = threadIdx.x, lane = tid & 63, wave = tid >> 6;
  int m0 = blockIdx.x*128, n0 = blockIdx.y*128;
  int wr = (wave>>1)*64, wc = (wave&1)*64;
  int row = lane & 15, kq = (lane>>4)*8;
  int rS = lane>>2, cS = (lane&3)*8;          // staging: lane covers row rS, elems cS..cS+7
  f32x4 acc[4][4];
  #pragma unroll
  for (int m=0;m<4;m++)
    #pragma unroll
    for (int n=0;n<4;n++)
      #pragma unroll
      for (int r=0;r<4;r++) acc[m][n][r] = 0.f;

  for (int k0=0;k0<K;k0+=32){
    __syncthreads();
    #pragma unroll
    for (int half=0; half<2; ++half){
      int rb = half*64 + wave*16;             // wave-uniform row base
      size_t gArow = (size_t)(m0 + rb + rS)*K + k0 + cS;
      size_t gBrow = (size_t)(n0 + rb + rS)*K + k0 + cS;
      gl_lds16(A2h + gArow, &sAh[rb*32]);
      gl_lds16(A2l + gArow, &sAl[rb*32]);
      gl_lds16(Bth + gBrow, &sBh[rb*32]);
      if (BSPLIT) gl_lds16(Btl + gBrow, &sBl[rb*32]);
    }
    __syncthreads();
    short8 ah[4], al[4], bh[4];
    #pragma unroll
    for (int m=0;m<4;m++){ ah[m] = *(const short8*)(&sAh[(wr + m*16 + row)*32 + kq]);
                           al[m] = *(const short8*)(&sAl[(wr + m*16 + row)*32 + kq]); }
    #pragma unroll
    for (int n=0;n<4;n++) bh[n] = *(const short8*)(&sBh[(wc + n*16 + row)*32 + kq]);
    #pragma unroll
    for (int m=0;m<4;m++)
      #pragma unroll
      for (int n=0;n<4;n++){
        acc[m][n] = __builtin_amdgcn_mfma_f32_16x16x32_bf16(ah[m], bh[n], acc[m][n], 0, 0, 0);
        acc[m][n] = __builtin_amdgcn_mfma_f32_16x16x32_bf16(al[m], bh[n], acc[m][n], 0, 0, 0);
      }
    if (BSPLIT){
      short8 bl[4];
      #pragma unroll
      for (int n=0;n<4;n++) bl[n] = *(const short8*)(&sBl[(wc + n*16 + row)*32 + kq]);
      #pragma unroll
      for (int m=0;m<4;m++)
        #pragma unroll
        for (int n=0;n<4;n++)
          acc[m][n] = __builtin_amdgcn_mfma_f32_16x16x32_bf16(ah[m], bl[n], acc[m][n], 0, 0, 0);
    }
  }
  #pragma unroll
  for (int m=0;m<4;m++)
    #pragma unroll
    for (int n=0;n<4;n++)
      #pragma unroll
      for (int r=0;r<4;r++){
        int rr = m0 + wr + m*16 + (lane>>4)*4 + r;
        int cc = n0 + wc + n*16 + (lane&15);
        C[(size_t)rr*N + cc] = f2bf(acc[m][n][r]);
      }
}

// ---------------- plain bf16 GEMM (final projection, fp32 out), global_load_lds staged ----------
__global__ __launch_bounds__(256) void k_gemm(const unsigned short* __restrict__ A,
                                              const unsigned short* __restrict__ Bt,
                                              float* __restrict__ C, int M, int N, int K){
  __shared__ unsigned short sA[4096];
  __shared__ unsigned short sB[4096];
  int tid = threadIdx.x, lane = tid & 63, wave = tid >> 6;
  int m0 = blockIdx.x*128, n0 = blockIdx.y*128;
  int wr = (wave>>1)*64, wc = (wave&1)*64;
  int row = lane & 15, kq = (lane>>4)*8;
  int rS = lane>>2, cS = (lane&3)*8;
  f32x4 acc[4][4];
  #pragma unroll
  for (int m=0;m<4;m++)
    #pragma unroll
    for (int n=0;n<4;n++)
      #pragma unroll
      for (int r=0;r<4;r++) acc[m][n][r] = 0.f;

  for (int k0=0;k0<K;k0+=32){
    __syncthreads();
    #pragma unroll
    for (int half=0; half<2; ++half){
      int rb = half*64 + wave*16;
      size_t gArow = (size_t)(m0 + rb + rS)*K + k0 + cS;
      size_t gBrow = (size_t)(n0 + rb + rS)*K + k0 + cS;
      gl_lds16(A  + gArow, &sA[rb*32]);
      gl_lds16(Bt + gBrow, &sB[rb*32]);
    }
    __syncthreads();
    short8 af[4], bfr[4];
    #pragma unroll
    for (int m=0;m<4;m++) af[m]  = *(const short8*)(&sA[(wr + m*16 + row)*32 + kq]);
    #pragma unroll
    for (int n=0;n<4;n++) bfr[n] = *(const short8*)(&sB[(wc + n*16 + row)*32 + kq]);
    #pragma unroll
    for (int m=0;m<4;m++)
      #pragma unroll
      for (int n=0;n<4;n++)
        acc[m][n] = __builtin_amdgcn_mfma_f32_16x16x32_bf16(af[m], bfr[n], acc[m][n], 0, 0, 0);
  }
  #pragma unroll
  for (int m=0;m<4;m++)
    #pragma unroll
    for (int n=0;n<4;n++)
      #pragma unroll
      for (int r=0;r<4;r++){
        int rr = m0 + wr + m*16 + (lane>>4)*4 + r;
        int cc = n0 + wc + n*16 + (lane&15);
        C[(size_t)rr*N + cc] = acc[m][n][r];
      }
}

// ---------------- exact fp32 alpha -> gk (pre-cumsum), layout G[(b*H+h)*T + t] ----------------
__global__ __launch_bounds__(256) void k_alpha(const float* __restrict__ hs, const float* __restrict__ Wa,
                                               const float* __restrict__ Al, const float* __restrict__ dtb,
                                               float* __restrict__ Gc){
  int rowi = blockIdx.x;
  int tid = threadIdx.x;
  const float* h = hs + (size_t)rowi*ND;
  float a0=0.f,a1=0.f,a2=0.f,a3=0.f;
  for (int d=tid; d<ND; d+=256){
    float x = h[d];
    a0 += x*Wa[d*4+0]; a1 += x*Wa[d*4+1]; a2 += x*Wa[d*4+2]; a3 += x*Wa[d*4+3];
  }
  #pragma unroll
  for (int off=32; off>0; off>>=1){
    a0 += __shfl_down(a0, off, 64); a1 += __shfl_down(a1, off, 64);
    a2 += __shfl_down(a2, off, 64); a3 += __shfl_down(a3, off, 64);
  }
  __shared__ float red[4][4];
  if ((tid&63)==0){ int w = tid>>6; red[w][0]=a0; red[w][1]=a1; red[w][2]=a2; red[w][3]=a3; }
  __syncthreads();
  if (tid < 4){
    float al = red[0][tid]+red[1][tid]+red[2][tid]+red[3][tid];
    float x = al + dtb[tid];
    float sp = (x > 20.f) ? x : log1pf(expf(x));
    float gkv = -expf(Al[tid]) * sp;
    int bb = rowi >> 13, t = rowi & (NT-1);
    Gc[((size_t)(bb*NH + tid))*NT + t] = gkv;
  }
}

// ---------------- inclusive cumsum over t in DOUBLE: Gd[bh][t] ----------------
__global__ __launch_bounds__(256) void k_cumsum(const float* __restrict__ Gc, double* __restrict__ Gd){
  int bh = blockIdx.x, tid = threadIdx.x;
  const float* g = Gc + (size_t)bh*NT;
  double* out = Gd + (size_t)bh*NT;
  __shared__ double wsum[4];
  __shared__ double carry_s;
  if (tid==0) carry_s = 0.0;
  __syncthreads();
  for (int t0=0; t0<NT; t0+=256){
    double v = (double)g[t0+tid];
    #pragma unroll
    for (int off=1; off<64; off<<=1){
      double y = shfl_up_dbl(v, off);
      if ((tid&63) >= off) v += y;
    }
    if ((tid&63)==63) wsum[tid>>6] = v;
    __syncthreads();
    double add = carry_s;
    for (int w=0; w<(tid>>6); ++w) add += wsum[w];
    v += add;
    out[t0+tid] = v;
    __syncthreads();
    if (tid==255) carry_s = v;
    __syncthreads();
  }
}

// ---- phase A (MFMA, per-chunk): S_loc^T[n][k] = sum_j exp(Gend-Gj) v_j k_j, bf16 out ----
__global__ __launch_bounds__(256) void k_phaseA(const unsigned short* __restrict__ kb,
                                                const unsigned short* __restrict__ vb,
                                                const double* __restrict__ Gd,
                                                unsigned short* __restrict__ Sbc){
  __shared__ unsigned short vT[16384];   // [256 n][64 j] swizzled
  __shared__ unsigned short wkT[8192];   // [128 k][64 j] swizzled
  int blk = blockIdx.x, bh = blockIdx.y;   // chunk, bh
  int bb = bh>>2, hh = bh&3;
  int cs = blk*CHK, tid = threadIdx.x;
  int lane = tid & 63, w = tid >> 6;
  const double* Gb = Gd + (size_t)bh*NT;
  double Gend = Gb[cs + 63];
  #pragma unroll
  for (int it=0; it<8; ++it){
    int task = it*256 + tid;
    int j = task & 63, ng = task >> 6;
    short8 vv = *(const short8*)(vb + (size_t)(bb*NT + cs + j)*NV + hh*NHV + ng*8);
    #pragma unroll
    for (int e=0;e<8;e++)
      *(unsigned short*)lds_at(vT, ng*8+e, j, 128) = (unsigned short)vv[e];
  }
  #pragma unroll
  for (int it=0; it<4; ++it){
    int task = it*256 + tid;
    int j = task & 63, kg = task >> 6;
    float wj = expf((float)(Gend - Gb[cs + j]));
    short8 kv = *(const short8*)(kb + (size_t)(bb*NT + cs + j)*NQK + hh*NHK + kg*8);
    #pragma unroll
    for (int e=0;e<8;e++)
      *(unsigned short*)lds_at(wkT, kg*8+e, j, 128) = f2bf(wj * bf2f((unsigned short)kv[e]));
  }
  __syncthreads();
  f32x4 sa[32];
  #pragma unroll
  for (int i=0;i<32;i++) sa[i] = (f32x4){0.f,0.f,0.f,0.f};
  short8 wa[2][2];
  #pragma unroll
  for (int mt=0;mt<2;mt++)
    #pragma unroll
    for (int kk=0;kk<2;kk++)
      wa[mt][kk] = *(short8*)lds_at(wkT, 32*w + mt*16 + (lane&15), kk*32 + (lane>>4)*8, 128);
  #pragma unroll
  for (int mt=0;mt<2;mt++)
    #pragma unroll
    for (int nt=0;nt<16;nt++)
      #pragma unroll
      for (int kk=0;kk<2;kk++){
        short8 b = *(short8*)lds_at(vT, nt*16 + (lane&15), kk*32 + (lane>>4)*8, 128);
        sa[mt*16+nt] = __builtin_amdgcn_mfma_f32_16x16x32_bf16(wa[mt][kk], b, sa[mt*16+nt], 0,0,0);
      }
  // write bf16 state [n][k]
  unsigned short* dst = Sbc + (size_t)(bh*NCHK + blk)*32768;
  #pragma unroll
  for (int mt=0;mt<2;mt++)
    #pragma unroll
    for (int nt=0;nt<16;nt++){
      int k = 32*w + mt*16 + (lane>>4)*4;
      int n = nt*16 + (lane&15);
      s16x4 p;
      #pragma unroll
      for (int r=0;r<4;r++) p[r] = (short)f2bf(sa[mt*16+nt][r]);
      *(s16x4*)(dst + (size_t)n*128 + k) = p;
    }
}

// ---------------- phase B: parallel elementwise scan over chunk states (bf16 io, fp32 run) ----
__global__ __launch_bounds__(256) void k_phaseB(unsigned short* __restrict__ Sbc,
                                                const double* __restrict__ Gd){
  int slice = blockIdx.x, bh = blockIdx.y;
  int tid = threadIdx.x;
  const double* Gb = Gd + (size_t)bh*NT;
  unsigned short* base = Sbc + (size_t)(bh*NCHK)*32768 + slice*1024 + tid*4;
  s16x4 c0 = *(const s16x4*)(base);
  f32x4 run;
  #pragma unroll
  for (int e=0;e<4;e++) run[e] = bf2f((unsigned short)c0[e]);
  s16x4 nxt = *(const s16x4*)(base + 32768);
  for (int b=1; b<NCHK; ++b){
    s16x4 cur = nxt;
    if (b+1 < NCHK) nxt = *(const s16x4*)(base + (size_t)(b+1)*32768);
    float resc = expf((float)(Gb[b*CHK + 63] - Gb[b*CHK - 1]));
    s16x4 outp;
    #pragma unroll
    for (int e=0;e<4;e++){
      run[e] = resc*run[e] + bf2f((unsigned short)cur[e]);
      outp[e] = (short)f2bf(run[e]);
    }
    *(s16x4*)(base + (size_t)b*32768) = outp;
  }
}

// ---- phase C (per-chunk): o = qg @ S^T + maskedP @ V, fused RMSNorm/gate, o2 in-place over g ----
__global__ __launch_bounds__(256) void k_phaseC(const unsigned short* __restrict__ qb,
                                                const unsigned short* __restrict__ kb,
                                                const unsigned short* __restrict__ vb,
                                                unsigned short* __restrict__ gio,
                                                const float* __restrict__ rmsw,
                                                const double* __restrict__ Gd,
                                                const unsigned short* __restrict__ Sbc,
                                                int dummy){
  __shared__ unsigned short vT[16384];   // [256 n][64 j] swizzled
  __shared__ unsigned short scp[4096];   // [64][64] swizzled
  __shared__ float Gsf[64];
  int blk = blockIdx.x, bh = blockIdx.y;   // chunk, bh
  int bb = bh>>2, hh = bh&3;
  int cs = blk*CHK, tid = threadIdx.x;
  int lane = tid&63, w = tid>>6;
  const double* Gb = Gd + (size_t)bh*NT;
  // stage vT + Gsf
  #pragma unroll
  for (int it=0; it<8; ++it){
    int task = it*256 + tid;
    int j = task & 63, ng = task >> 6;
    short8 vv = *(const short8*)(vb + (size_t)(bb*NT + cs + j)*NV + hh*NHV + ng*8);
    #pragma unroll
    for (int e=0;e<8;e++)
      *(unsigned short*)lds_at(vT, ng*8+e, j, 128) = (unsigned short)vv[e];
  }
  if (tid < 64){
    double ref = (cs == 0) ? 0.0 : Gb[cs-1];
    Gsf[tid] = (float)(Gb[cs+tid] - ref);
  }
  __syncthreads();
  int irow = 16*w + (lane&15);
  // q fragments direct from global
  const unsigned short* qrow = qb + (size_t)(bb*NT + cs + irow)*NQK + hh*NHK;
  short8 qaraw[4], qag[4];
  float si = SCALE * expf(Gsf[irow]);
  #pragma unroll
  for (int kk=0;kk<4;kk++){
    short8 a = *(const short8*)(qrow + kk*32 + (lane>>4)*8);
    qaraw[kk] = a;
    short8 g;
    #pragma unroll
    for (int e=0;e<8;e++) g[e] = (short)f2bf(si * bf2f((unsigned short)a[e]));
    qag[kk] = g;
  }
  // P = q @ k^T (k fragments direct from global)
  f32x4 pa[4];
  #pragma unroll
  for (int jt=0;jt<4;jt++) pa[jt] = (f32x4){0.f,0.f,0.f,0.f};
  #pragma unroll
  for (int jt=0;jt<4;jt++)
    #pragma unroll
    for (int kk=0;kk<4;kk++){
      short8 b = *(const short8*)(kb + (size_t)(bb*NT + cs + jt*16 + (lane&15))*NQK
                                  + hh*NHK + kk*32 + (lane>>4)*8);
      pa[jt] = __builtin_amdgcn_mfma_f32_16x16x32_bf16(qaraw[kk], b, pa[jt], 0,0,0);
    }
  // weight + causal mask on fragments -> scp (bf16)
  #pragma unroll
  for (int jt=0;jt<4;jt++)
    #pragma unroll
    for (int r=0;r<4;r++){
      int il = 16*w + (lane>>4)*4 + r;
      int jl = jt*16 + (lane&15);
      float wgt = (jl <= il) ? SCALE * expf(Gsf[il] - Gsf[jl]) : 0.f;
      *(unsigned short*)lds_at(scp, il, jl, 128) = f2bf(wgt * pa[jt][r]);
    }
  // o_inter: S fragments direct from global (state after chunk blk-1)
  f32x4 oa[16];
  #pragma unroll
  for (int nt=0;nt<16;nt++) oa[nt] = (f32x4){0.f,0.f,0.f,0.f};
  if (blk > 0){
    const unsigned short* Sst = Sbc + (size_t)(bh*NCHK + blk - 1)*32768;
    #pragma unroll
    for (int nt=0;nt<16;nt++)
      #pragma unroll
      for (int kk=0;kk<4;kk++){
        short8 b = *(const short8*)(Sst + (size_t)(nt*16 + (lane&15))*128 + kk*32 + (lane>>4)*8);
        oa[nt] = __builtin_amdgcn_mfma_f32_16x16x32_bf16(qag[kk], b, oa[nt], 0,0,0);
      }
  }
  __syncthreads();   // scp written by all waves
  // o += scp @ vT^T (K=64)
  short8 sa2[2];
  #pragma unroll
  for (int kk=0;kk<2;kk++)
    sa2[kk] = *(short8*)lds_at(scp, irow, kk*32 + (lane>>4)*8, 128);
  #pragma unroll
  for (int nt=0;nt<16;nt++)
    #pragma unroll
    for (int kk=0;kk<2;kk++){
      short8 b = *(short8*)lds_at(vT, nt*16 + (lane&15), kk*32 + (lane>>4)*8, 128);
      oa[nt] = __builtin_amdgcn_mfma_f32_16x16x32_bf16(sa2[kk], b, oa[nt], 0,0,0);
    }
  // epilogue: RMSNorm over n + swish gate
  float p4[4] = {0.f,0.f,0.f,0.f};
  #pragma unroll
  for (int nt=0;nt<16;nt++)
    #pragma unroll
    for (int r=0;r<4;r++) p4[r] += oa[nt][r]*oa[nt][r];
  #pragma unroll
  for (int r=0;r<4;r++){
    #pragma unroll
    for (int off=1; off<16; off<<=1) p4[r] += __shfl_xor(p4[r], off, 16);
  }
  float fr[4];
  #pragma unroll
  for (int r=0;r<4;r++) fr[r] = rsqrtf(p4[r]*(1.f/256.f) + 1e-5f);
  #pragma unroll
  for (int nt=0;nt<16;nt++)
    #pragma unroll
    for (int r=0;r<4;r++){
      int tg = cs + 16*w + (lane>>4)*4 + r;
      int n = nt*16 + (lane&15);
      size_t gidx = (size_t)(bb*NT + tg)*NV + hh*NHV + n;
      float gv = bf2f(gio[gidx]);
      float sw = gv / (1.f + expf(-gv));
      gio[gidx] = f2bf(oa[nt][r] * fr[r] * rmsw[n] * sw);
    }
  (void)dummy;
}

// ---------------- launch ----------------
extern "C" void kernel_launch(void* const* d_in, const int* in_sizes, int n_in,
                              void* d_out, int out_size, void* d_ws, size_t ws_size,
                              hipStream_t stream) {
  (void)in_sizes; (void)n_in; (void)out_size;
  const float* hs  = (const float*)d_in[0];
  const float* Wq  = (const float*)d_in[1];
  const float* Wk  = (const float*)d_in[2];
  const float* Wv  = (const float*)d_in[3];
  const float* Wa  = (const float*)d_in[4];
  const float* Wg  = (const float*)d_in[5];
  const float* Wo  = (const float*)d_in[6];
  const float* Al  = (const float*)d_in[7];
  const float* dtb = (const float*)d_in[8];
  const float* rmsw= (const float*)d_in[9];
  char* ws = (char*)d_ws;

  // workspace layout — total stays within known-safe 176,947,200 B
  constexpr size_t MB = 1048576;
  constexpr size_t OFF_Q    = 0;            // 16MB bf16 q
  constexpr size_t OFF_K    = 16*MB;        // 16MB bf16 k
  constexpr size_t OFF_V    = 32*MB;        // 32MB bf16 v
  constexpr size_t OFF_G    = 64*MB;        // 32MB bf16 gate -> o2 in-place
  constexpr size_t OFF_WQH  = 96*MB;        // 1MB
  constexpr size_t OFF_WQL  = 97*MB;        // 1MB
  constexpr size_t OFF_WKH  = 98*MB;        // 1MB
  constexpr size_t OFF_WKL  = 99*MB;        // 1MB
  constexpr size_t OFF_WV   = 100*MB;       // 2MB
  constexpr size_t OFF_WG   = 102*MB;       // 2MB
  constexpr size_t OFF_WO   = 104*MB;       // 2MB
  constexpr size_t OFF_GC   = 106*MB;                 // 256KB
  constexpr size_t OFF_GD   = 106*MB + 262144;        // 512KB
  constexpr size_t OFF_SBC  = 107*MB;       // 64MB bf16 chunk states; hsh/hsl alias here pre-phaseA
  constexpr size_t WS_REQUIRED = 176947200;
  if (ws_size < WS_REQUIRED) return;

  unsigned short* qb  = (unsigned short*)(ws + OFF_Q);
  unsigned short* kb  = (unsigned short*)(ws + OFF_K);
  unsigned short* vb  = (unsigned short*)(ws + OFF_V);
  unsigned short* gb  = (unsigned short*)(ws + OFF_G);
  unsigned short* wqh = (unsigned short*)(ws + OFF_WQH);
  unsigned short* wql = (unsigned short*)(ws + OFF_WQL);
  unsigned short* wkh = (unsigned short*)(ws + OFF_WKH);
  unsigned short* wkl = (unsigned short*)(ws + OFF_WKL);
  unsigned short* wvt = (unsigned short*)(ws + OFF_WV);
  unsigned short* wgt = (unsigned short*)(ws + OFF_WG);
  unsigned short* wot = (unsigned short*)(ws + OFF_WO);
  float* Gc   = (float*)(ws + OFF_GC);
  double* Gd  = (double*)(ws + OFF_GD);
  unsigned short* Sbc = (unsigned short*)(ws + OFF_SBC);
  unsigned short* hsh = (unsigned short*)(ws + OFF_SBC);          // 32MB, dead before phaseA
  unsigned short* hsl = (unsigned short*)(ws + OFF_SBC + 32*MB);  // 32MB, dead before phaseA

  // hs hi/lo split + weight transposes
  k_split<<<8192, 256, 0, stream>>>(hs, hsh, hsl, NB*NT*ND);
  k_tc2<<<2048, 256, 0, stream>>>(Wq, wqh, wql, 1024, 512);
  k_tc2<<<2048, 256, 0, stream>>>(Wk, wkh, wkl, 1024, 512);
  k_tc <<<4096, 256, 0, stream>>>(Wv, wvt, 1024, 1024);
  k_tc <<<4096, 256, 0, stream>>>(Wg, wgt, 1024, 1024);
  k_tc <<<4096, 256, 0, stream>>>(Wo, wot, 1024, 1024);

  // projections (A = hs_hi + hs_lo, bf16 staged via global_load_lds)
  k_gemm2<1><<<dim3(128,4), 256, 0, stream>>>(hsh, hsl, wqh, wql, qb, 16384, 512, 1024);
  k_gemm2<1><<<dim3(128,4), 256, 0, stream>>>(hsh, hsl, wkh, wkl, kb, 16384, 512, 1024);
  k_gemm2<0><<<dim3(128,8), 256, 0, stream>>>(hsh, hsl, wvt, nullptr, vb, 16384, 1024, 1024);
  k_gemm2<0><<<dim3(128,8), 256, 0, stream>>>(hsh, hsl, wgt, nullptr, gb, 16384, 1024, 1024);

  k_alpha<<<16384, 256, 0, stream>>>(hs, Wa, Al, dtb, Gc);
  k_cumsum<<<8, 256, 0, stream>>>(Gc, Gd);

  k_phaseA<<<dim3(NCHK,8), 256, 0, stream>>>(kb, vb, Gd, Sbc);
  k_phaseB<<<dim3(32,8), 256, 0, stream>>>(Sbc, Gd);
  k_phaseC<<<dim3(NCHK,8), 256, 0, stream>>>(qb, kb, vb, gb, rmsw, Gd, Sbc, 0);

  // final GEMM: o2 (= gb region) @ Wo^T
  k_gemm<<<dim3(128,8), 256, 0, stream>>>(gb, wot, (float*)d_out, 16384, 1024, 1024);
}

// Round 9
// 512.323 us; speedup vs baseline: 1.1489x; 1.1097x over previous
//
#include <hip/hip_runtime.h>
#include <cstdint>
#include <cstddef>

// Problem constants
#define NB 2
#define NT 8192
#define ND 1024
#define NH 4
#define NQK 512
#define NV 1024
#define NHK 128
#define NHV 256
#define CHK 64
#define NCHK 128            // chunks per (b,h)
#define SCALE 0.08838834764831845f   // HK^-0.5

using f32x4 = __attribute__((ext_vector_type(4))) float;
using short8 = __attribute__((ext_vector_type(8))) short;
using s16x4 = __attribute__((ext_vector_type(4))) short;

__device__ __forceinline__ float bf2f(unsigned short u){
  union { unsigned int i; float f; } t; t.i = ((unsigned int)u) << 16; return t.f;
}
__device__ __forceinline__ unsigned short f2bf(float f){
  union { float f; unsigned int i; } t; t.f = f;
  unsigned int r = t.i + 0x7fffu + ((t.i >> 16) & 1u);
  return (unsigned short)(r >> 16);
}
__device__ __forceinline__ double shfl_up_dbl(double v, int off){
  union { double d; unsigned int u[2]; } a, r;
  a.d = v;
  r.u[0] = __shfl_up(a.u[0], off, 64);
  r.u[1] = __shfl_up(a.u[1], off, 64);
  return r.d;
}
// Swizzled LDS accessor for bf16 tiles: row-major, rowBytes in {128,256}.
__device__ __forceinline__ void* lds_at(void* base, int row, int colElem, int rowBytes){
  return (void*)((char*)base + row*rowBytes + (((colElem*2) ^ ((row&7)<<4))));
}
// swizzle for the [64][256] bf16 o-tile (512B rows): spread (row>>2) groups across banks
__device__ __forceinline__ int osw(int rowl, int byteoff){
  return rowl*512 + (byteoff ^ (((rowl>>2)&7)<<4));
}

// ---- async global->LDS, 16B per lane; dest is wave-uniform base + lane*16 (m97 pattern) ----
typedef const __attribute__((address_space(1))) unsigned int as1_u32;
typedef __attribute__((address_space(3))) unsigned int as3_u32;
__device__ __forceinline__ void gl_lds16(const void* g_lane, void* lds_uniform){
  __builtin_amdgcn_global_load_lds((as1_u32*)(uintptr_t)g_lane,
                                   (as3_u32*)(unsigned int)(uintptr_t)lds_uniform,
                                   16, 0, 0);
}

// ---------------- weight transpose+cast (single): dst[c][r] = bf16(src[r][c]) ----------------
__global__ __launch_bounds__(256) void k_tc(const float* __restrict__ src,
                                            unsigned short* __restrict__ dst, int R, int C){
  int idx = blockIdx.x*256 + threadIdx.x;
  if (idx >= R*C) return;
  int r = idx % R, c = idx / R;
  dst[(size_t)c*R + r] = f2bf(src[(size_t)r*C + c]);
}

// ---------------- weight transpose+cast hi/lo pair ----------------
__global__ __launch_bounds__(256) void k_tc2(const float* __restrict__ src,
                                             unsigned short* __restrict__ dh,
                                             unsigned short* __restrict__ dl, int R, int C){
  int idx = blockIdx.x*256 + threadIdx.x;
  if (idx >= R*C) return;
  int r = idx % R, c = idx / R;
  float x = src[(size_t)r*C + c];
  unsigned short h = f2bf(x);
  unsigned short l = f2bf(x - bf2f(h));
  dh[(size_t)c*R + r] = h;
  dl[(size_t)c*R + r] = l;
}

// ---------------- split fp32 -> (hi,lo) bf16, 8 elems/thread ----------------
__global__ __launch_bounds__(256) void k_split(const float* __restrict__ s,
                                               unsigned short* __restrict__ dh,
                                               unsigned short* __restrict__ dl, int n){
  int i = (blockIdx.x*256 + threadIdx.x)*8;
  if (i >= n) return;
  f32x4 x0 = *(const f32x4*)(s+i);
  f32x4 x1 = *(const f32x4*)(s+i+4);
  short8 h8, l8;
  #pragma unroll
  for (int e=0;e<4;e++){
    unsigned short h0 = f2bf(x0[e]); h8[e]   = (short)h0; l8[e]   = (short)f2bf(x0[e] - bf2f(h0));
    unsigned short h1 = f2bf(x1[e]); h8[e+4] = (short)h1; l8[e+4] = (short)f2bf(x1[e] - bf2f(h1));
  }
  *(short8*)(dh+i) = h8;
  *(short8*)(dl+i) = l8;
}

// ------- GEMM (global_load_lds staged): C = A@Bt^T with optional A-lo and B-lo passes -------
template<int ASPLIT, int BSPLIT>
__global__ __launch_bounds__(256) void k_gemm2(const unsigned short* __restrict__ A2h,
                                               const unsigned short* __restrict__ A2l,
                                               const unsigned short* __restrict__ Bth,
                                               const unsigned short* __restrict__ Btl,
                                               unsigned short* __restrict__ C, int M, int N, int K){
  // linear [128][32] bf16 buffers (64B rows), contiguous for global_load_lds
  __shared__ unsigned short sAh[4096];
  __shared__ unsigned short sAl[4096];
  __shared__ unsigned short sBh[4096];
  __shared__ unsigned short sBl[4096];
  int tid = threadIdx.x, lane = tid & 63, wave = tid >> 6;
  int m0 = blockIdx.x*128, n0 = blockIdx.y*128;
  int wr = (wave>>1)*64, wc = (wave&1)*64;
  int row = lane & 15, kq = (lane>>4)*8;
  int rS = lane>>2, cS = (lane&3)*8;          // staging: lane covers row rS, elems cS..cS+7
  f32x4 acc[4][4];
  #pragma unroll
  for (int m=0;m<4;m++)
    #pragma unroll
    for (int n=0;n<4;n++)
      #pragma unroll
      for (int r=0;r<4;r++) acc[m][n][r] = 0.f;

  for (int k0=0;k0<K;k0+=32){
    __syncthreads();
    #pragma unroll
    for (int half=0; half<2; ++half){
      int rb = half*64 + wave*16;             // wave-uniform row base
      size_t gArow = (size_t)(m0 + rb + rS)*K + k0 + cS;
      size_t gBrow = (size_t)(n0 + rb + rS)*K + k0 + cS;
      gl_lds16(A2h + gArow, &sAh[rb*32]);
      if (ASPLIT) gl_lds16(A2l + gArow, &sAl[rb*32]);
      gl_lds16(Bth + gBrow, &sBh[rb*32]);
      if (BSPLIT) gl_lds16(Btl + gBrow, &sBl[rb*32]);
    }
    __syncthreads();
    short8 ah[4], bh[4];
    #pragma unroll
    for (int m=0;m<4;m++) ah[m] = *(const short8*)(&sAh[(wr + m*16 + row)*32 + kq]);
    #pragma unroll
    for (int n=0;n<4;n++) bh[n] = *(const short8*)(&sBh[(wc + n*16 + row)*32 + kq]);
    #pragma unroll
    for (int m=0;m<4;m++)
      #pragma unroll
      for (int n=0;n<4;n++)
        acc[m][n] = __builtin_amdgcn_mfma_f32_16x16x32_bf16(ah[m], bh[n], acc[m][n], 0, 0, 0);
    if (ASPLIT){
      short8 al[4];
      #pragma unroll
      for (int m=0;m<4;m++) al[m] = *(const short8*)(&sAl[(wr + m*16 + row)*32 + kq]);
      #pragma unroll
      for (int m=0;m<4;m++)
        #pragma unroll
        for (int n=0;n<4;n++)
          acc[m][n] = __builtin_amdgcn_mfma_f32_16x16x32_bf16(al[m], bh[n], acc[m][n], 0, 0, 0);
    }
    if (BSPLIT){
      short8 bl[4];
      #pragma unroll
      for (int n=0;n<4;n++) bl[n] = *(const short8*)(&sBl[(wc + n*16 + row)*32 + kq]);
      #pragma unroll
      for (int m=0;m<4;m++)
        #pragma unroll
        for (int n=0;n<4;n++)
          acc[m][n] = __builtin_amdgcn_mfma_f32_16x16x32_bf16(ah[m], bl[n], acc[m][n], 0, 0, 0);
    }
  }
  #pragma unroll
  for (int m=0;m<4;m++)
    #pragma unroll
    for (int n=0;n<4;n++)
      #pragma unroll
      for (int r=0;r<4;r++){
        int rr = m0 + wr + m*16 + (lane>>4)*4 + r;
        int cc = n0 + wc + n*16 + (lane&15);
        C[(size_t)rr*N + cc] = f2bf(acc[m][n][r]);
      }
}

// ---------------- plain bf16 GEMM (final projection, fp32 out), global_load_lds staged ----------
__global__ __launch_bounds__(256) void k_gemm(const unsigned short* __restrict__ A,
                                              const unsigned short* __restrict__ Bt,
                                              float* __restrict__ C, int M, int N, int K){
  __shared__ unsigned short sA[4096];
  __shared__ unsigned short sB[4096];
  int tid = threadIdx.x, lane = tid & 63, wave = tid >> 6;
  int m0 = blockIdx.x*128, n0 = blockIdx.y*128;
  int wr = (wave>>1)*64, wc = (wave&1)*64;
  int row = lane & 15, kq = (lane>>4)*8;
  int rS = lane>>2, cS = (lane&3)*8;
  f32x4 acc[4][4];
  #pragma unroll
  for (int m=0;m<4;m++)
    #pragma unroll
    for (int n=0;n<4;n++)
      #pragma unroll
      for (int r=0;r<4;r++) acc[m][n][r] = 0.f;

  for (int k0=0;k0<K;k0+=32){
    __syncthreads();
    #pragma unroll
    for (int half=0; half<2; ++half){
      int rb = half*64 + wave*16;
      size_t gArow = (size_t)(m0 + rb + rS)*K + k0 + cS;
      size_t gBrow = (size_t)(n0 + rb + rS)*K + k0 + cS;
      gl_lds16(A  + gArow, &sA[rb*32]);
      gl_lds16(Bt + gBrow, &sB[rb*32]);
    }
    __syncthreads();
    short8 af[4], bfr[4];
    #pragma unroll
    for (int m=0;m<4;m++) af[m]  = *(const short8*)(&sA[(wr + m*16 + row)*32 + kq]);
    #pragma unroll
    for (int n=0;n<4;n++) bfr[n] = *(const short8*)(&sB[(wc + n*16 + row)*32 + kq]);
    #pragma unroll
    for (int m=0;m<4;m++)
      #pragma unroll
      for (int n=0;n<4;n++)
        acc[m][n] = __builtin_amdgcn_mfma_f32_16x16x32_bf16(af[m], bfr[n], acc[m][n], 0, 0, 0);
  }
  #pragma unroll
  for (int m=0;m<4;m++)
    #pragma unroll
    for (int n=0;n<4;n++)
      #pragma unroll
      for (int r=0;r<4;r++){
        int rr = m0 + wr + m*16 + (lane>>4)*4 + r;
        int cc = n0 + wc + n*16 + (lane&15);
        C[(size_t)rr*N + cc] = acc[m][n][r];
      }
}

// ---------------- exact fp32 alpha -> gk (pre-cumsum), layout G[(b*H+h)*T + t] ----------------
__global__ __launch_bounds__(256) void k_alpha(const float* __restrict__ hs, const float* __restrict__ Wa,
                                               const float* __restrict__ Al, const float* __restrict__ dtb,
                                               float* __restrict__ Gc){
  int rowi = blockIdx.x;
  int tid = threadIdx.x;
  const float* h = hs + (size_t)rowi*ND;
  float a0=0.f,a1=0.f,a2=0.f,a3=0.f;
  for (int d=tid; d<ND; d+=256){
    float x = h[d];
    a0 += x*Wa[d*4+0]; a1 += x*Wa[d*4+1]; a2 += x*Wa[d*4+2]; a3 += x*Wa[d*4+3];
  }
  #pragma unroll
  for (int off=32; off>0; off>>=1){
    a0 += __shfl_down(a0, off, 64); a1 += __shfl_down(a1, off, 64);
    a2 += __shfl_down(a2, off, 64); a3 += __shfl_down(a3, off, 64);
  }
  __shared__ float red[4][4];
  if ((tid&63)==0){ int w = tid>>6; red[w][0]=a0; red[w][1]=a1; red[w][2]=a2; red[w][3]=a3; }
  __syncthreads();
  if (tid < 4){
    float al = red[0][tid]+red[1][tid]+red[2][tid]+red[3][tid];
    float x = al + dtb[tid];
    float sp = (x > 20.f) ? x : log1pf(expf(x));
    float gkv = -expf(Al[tid]) * sp;
    int bb = rowi >> 13, t = rowi & (NT-1);
    Gc[((size_t)(bb*NH + tid))*NT + t] = gkv;
  }
}

// ---------------- inclusive cumsum over t in DOUBLE: Gd[bh][t] ----------------
__global__ __launch_bounds__(256) void k_cumsum(const float* __restrict__ Gc, double* __restrict__ Gd){
  int bh = blockIdx.x, tid = threadIdx.x;
  const float* g = Gc + (size_t)bh*NT;
  double* out = Gd + (size_t)bh*NT;
  __shared__ double wsum[4];
  __shared__ double carry_s;
  if (tid==0) carry_s = 0.0;
  __syncthreads();
  for (int t0=0; t0<NT; t0+=256){
    double v = (double)g[t0+tid];
    #pragma unroll
    for (int off=1; off<64; off<<=1){
      double y = shfl_up_dbl(v, off);
      if ((tid&63) >= off) v += y;
    }
    if ((tid&63)==63) wsum[tid>>6] = v;
    __syncthreads();
    double add = carry_s;
    for (int w=0; w<(tid>>6); ++w) add += wsum[w];
    v += add;
    out[t0+tid] = v;
    __syncthreads();
    if (tid==255) carry_s = v;
    __syncthreads();
  }
}

// ---- phase A (MFMA, per-chunk): S_loc^T[n][k] = sum_j exp(Gend-Gj) v_j k_j, bf16 out ----
__global__ __launch_bounds__(256) void k_phaseA(const unsigned short* __restrict__ kb,
                                                const unsigned short* __restrict__ vb,
                                                const double* __restrict__ Gd,
                                                unsigned short* __restrict__ Sbc){
  __shared__ unsigned short vT[16384];   // [256 n][64 j] swizzled
  __shared__ unsigned short wkT[8192];   // [128 k][64 j] swizzled
  int blk = blockIdx.x, bh = blockIdx.y;   // chunk, bh
  int bb = bh>>2, hh = bh&3;
  int cs = blk*CHK, tid = threadIdx.x;
  int lane = tid & 63, w = tid >> 6;
  const double* Gb = Gd + (size_t)bh*NT;
  double Gend = Gb[cs + 63];
  #pragma unroll
  for (int it=0; it<8; ++it){
    int task = it*256 + tid;
    int j = task & 63, ng = task >> 6;
    short8 vv = *(const short8*)(vb + (size_t)(bb*NT + cs + j)*NV + hh*NHV + ng*8);
    #pragma unroll
    for (int e=0;e<8;e++)
      *(unsigned short*)lds_at(vT, ng*8+e, j, 128) = (unsigned short)vv[e];
  }
  #pragma unroll
  for (int it=0; it<4; ++it){
    int task = it*256 + tid;
    int j = task & 63, kg = task >> 6;
    float wj = expf((float)(Gend - Gb[cs + j]));
    short8 kv = *(const short8*)(kb + (size_t)(bb*NT + cs + j)*NQK + hh*NHK + kg*8);
    #pragma unroll
    for (int e=0;e<8;e++)
      *(unsigned short*)lds_at(wkT, kg*8+e, j, 128) = f2bf(wj * bf2f((unsigned short)kv[e]));
  }
  __syncthreads();
  f32x4 sa[32];
  #pragma unroll
  for (int i=0;i<32;i++) sa[i] = (f32x4){0.f,0.f,0.f,0.f};
  short8 wa[2][2];
  #pragma unroll
  for (int mt=0;mt<2;mt++)
    #pragma unroll
    for (int kk=0;kk<2;kk++)
      wa[mt][kk] = *(short8*)lds_at(wkT, 32*w + mt*16 + (lane&15), kk*32 + (lane>>4)*8, 128);
  #pragma unroll
  for (int mt=0;mt<2;mt++)
    #pragma unroll
    for (int nt=0;nt<16;nt++)
      #pragma unroll
      for (int kk=0;kk<2;kk++){
        short8 b = *(short8*)lds_at(vT, nt*16 + (lane&15), kk*32 + (lane>>4)*8, 128);
        sa[mt*16+nt] = __builtin_amdgcn_mfma_f32_16x16x32_bf16(wa[mt][kk], b, sa[mt*16+nt], 0,0,0);
      }
  // write bf16 state [n][k]
  unsigned short* dst = Sbc + (size_t)(bh*NCHK + blk)*32768;
  #pragma unroll
  for (int mt=0;mt<2;mt++)
    #pragma unroll
    for (int nt=0;nt<16;nt++){
      int k = 32*w + mt*16 + (lane>>4)*4;
      int n = nt*16 + (lane&15);
      s16x4 p;
      #pragma unroll
      for (int r=0;r<4;r++) p[r] = (short)f2bf(sa[mt*16+nt][r]);
      *(s16x4*)(dst + (size_t)n*128 + k) = p;
    }
}

// ---------------- phase B: parallel elementwise scan over chunk states (bf16 io, fp32 run) ----
__global__ __launch_bounds__(256) void k_phaseB(unsigned short* __restrict__ Sbc,
                                                const double* __restrict__ Gd){
  int slice = blockIdx.x, bh = blockIdx.y;
  int tid = threadIdx.x;
  const double* Gb = Gd + (size_t)bh*NT;
  unsigned short* base = Sbc + (size_t)(bh*NCHK)*32768 + slice*1024 + tid*4;
  s16x4 c0 = *(const s16x4*)(base);
  f32x4 run;
  #pragma unroll
  for (int e=0;e<4;e++) run[e] = bf2f((unsigned short)c0[e]);
  s16x4 nxt = *(const s16x4*)(base + 32768);
  for (int b=1; b<NCHK; ++b){
    s16x4 cur = nxt;
    if (b+1 < NCHK) nxt = *(const s16x4*)(base + (size_t)(b+1)*32768);
    float resc = expf((float)(Gb[b*CHK + 63] - Gb[b*CHK - 1]));
    s16x4 outp;
    #pragma unroll
    for (int e=0;e<4;e++){
      run[e] = resc*run[e] + bf2f((unsigned short)cur[e]);
      outp[e] = (short)f2bf(run[e]);
    }
    *(s16x4*)(base + (size_t)b*32768) = outp;
  }
}

// ---- phase C (per-chunk): o = qg @ S^T + maskedP @ V, fused RMSNorm/gate, o2 in-place over g ----
__global__ __launch_bounds__(256) void k_phaseC(const unsigned short* __restrict__ qb,
                                                const unsigned short* __restrict__ kb,
                                                const unsigned short* __restrict__ vb,
                                                unsigned short* __restrict__ gio,
                                                const float* __restrict__ rmsw,
                                                const double* __restrict__ Gd,
                                                const unsigned short* __restrict__ Sbc,
                                                int dummy){
  __shared__ unsigned short vT[16384];   // [256 n][64 j] swizzled; reused as o-tile [64][256]
  __shared__ unsigned short scp[4096];   // [64][64] swizzled
  __shared__ float Gsf[64];
  __shared__ float rms_s[256];
  int blk = blockIdx.x, bh = blockIdx.y;   // chunk, bh
  int bb = bh>>2, hh = bh&3;
  int cs = blk*CHK, tid = threadIdx.x;
  int lane = tid&63, w = tid>>6;
  const double* Gb = Gd + (size_t)bh*NT;
  // stage vT + Gsf + rmsw
  #pragma unroll
  for (int it=0; it<8; ++it){
    int task = it*256 + tid;
    int j = task & 63, ng = task >> 6;
    short8 vv = *(const short8*)(vb + (size_t)(bb*NT + cs + j)*NV + hh*NHV + ng*8);
    #pragma unroll
    for (int e=0;e<8;e++)
      *(unsigned short*)lds_at(vT, ng*8+e, j, 128) = (unsigned short)vv[e];
  }
  rms_s[tid] = rmsw[tid];
  if (tid < 64){
    double ref = (cs == 0) ? 0.0 : Gb[cs-1];
    Gsf[tid] = (float)(Gb[cs+tid] - ref);
  }
  __syncthreads();
  int irow = 16*w + (lane&15);
  // q fragments direct from global
  const unsigned short* qrow = qb + (size_t)(bb*NT + cs + irow)*NQK + hh*NHK;
  short8 qaraw[4], qag[4];
  float si = SCALE * expf(Gsf[irow]);
  #pragma unroll
  for (int kk=0;kk<4;kk++){
    short8 a = *(const short8*)(qrow + kk*32 + (lane>>4)*8);
    qaraw[kk] = a;
    short8 g;
    #pragma unroll
    for (int e=0;e<8;e++) g[e] = (short)f2bf(si * bf2f((unsigned short)a[e]));
    qag[kk] = g;
  }
  // P = q @ k^T (k fragments direct from global)
  f32x4 pa[4];
  #pragma unroll
  for (int jt=0;jt<4;jt++) pa[jt] = (f32x4){0.f,0.f,0.f,0.f};
  #pragma unroll
  for (int jt=0;jt<4;jt++)
    #pragma unroll
    for (int kk=0;kk<4;kk++){
      short8 b = *(const short8*)(kb + (size_t)(bb*NT + cs + jt*16 + (lane&15))*NQK
                                  + hh*NHK + kk*32 + (lane>>4)*8);
      pa[jt] = __builtin_amdgcn_mfma_f32_16x16x32_bf16(qaraw[kk], b, pa[jt], 0,0,0);
    }
  // weight + causal mask on fragments -> scp (bf16)
  #pragma unroll
  for (int jt=0;jt<4;jt++)
    #pragma unroll
    for (int r=0;r<4;r++){
      int il = 16*w + (lane>>4)*4 + r;
      int jl = jt*16 + (lane&15);
      float wgt = (jl <= il) ? SCALE * expf(Gsf[il] - Gsf[jl]) : 0.f;
      *(unsigned short*)lds_at(scp, il, jl, 128) = f2bf(wgt * pa[jt][r]);
    }
  // o_inter: S fragments direct from global (state after chunk blk-1)
  f32x4 oa[16];
  #pragma unroll
  for (int nt=0;nt<16;nt++) oa[nt] = (f32x4){0.f,0.f,0.f,0.f};
  if (blk > 0){
    const unsigned short* Sst = Sbc + (size_t)(bh*NCHK + blk - 1)*32768;
    #pragma unroll
    for (int nt=0;nt<16;nt++)
      #pragma unroll
      for (int kk=0;kk<4;kk++){
        short8 b = *(const short8*)(Sst + (size_t)(nt*16 + (lane&15))*128 + kk*32 + (lane>>4)*8);
        oa[nt] = __builtin_amdgcn_mfma_f32_16x16x32_bf16(qag[kk], b, oa[nt], 0,0,0);
      }
  }
  __syncthreads();   // scp written by all waves
  // o += scp @ vT^T (K=64)
  short8 sa2[2];
  #pragma unroll
  for (int kk=0;kk<2;kk++)
    sa2[kk] = *(short8*)lds_at(scp, irow, kk*32 + (lane>>4)*8, 128);
  #pragma unroll
  for (int nt=0;nt<16;nt++)
    #pragma unroll
    for (int kk=0;kk<2;kk++){
      short8 b = *(short8*)lds_at(vT, nt*16 + (lane&15), kk*32 + (lane>>4)*8, 128);
      oa[nt] = __builtin_amdgcn_mfma_f32_16x16x32_bf16(sa2[kk], b, oa[nt], 0,0,0);
    }
  // epilogue: RMSNorm over n (shuffle over 16-lane groups) -> scaled o into LDS (vT reused)
  float p4[4] = {0.f,0.f,0.f,0.f};
  #pragma unroll
  for (int nt=0;nt<16;nt++)
    #pragma unroll
    for (int r=0;r<4;r++) p4[r] += oa[nt][r]*oa[nt][r];
  #pragma unroll
  for (int r=0;r<4;r++){
    #pragma unroll
    for (int off=1; off<16; off<<=1) p4[r] += __shfl_xor(p4[r], off, 16);
  }
  float fr[4];
  #pragma unroll
  for (int r=0;r<4;r++) fr[r] = rsqrtf(p4[r]*(1.f/256.f) + 1e-5f);
  __syncthreads();   // all waves done reading vT (PV complete) -> safe to overwrite
  char* oLDS = (char*)vT;    // [64][256] bf16, bank-swizzled via osw
  #pragma unroll
  for (int nt=0;nt<16;nt++){
    int n = nt*16 + (lane&15);
    float rw = rms_s[n];
    #pragma unroll
    for (int r=0;r<4;r++){
      int rowl = 16*w + (lane>>4)*4 + r;
      *(unsigned short*)(oLDS + osw(rowl, n*2)) = f2bf(oa[nt][r] * fr[r] * rw);
    }
  }
  __syncthreads();
  // coalesced gate pass: load g short8, multiply by swish, store o2 short8
  #pragma unroll
  for (int it=0; it<8; ++it){
    int task = it*256 + tid;
    int rowl = task >> 5, c8 = (task & 31)*8;
    size_t gbase = (size_t)(bb*NT + cs + rowl)*NV + hh*NHV + c8;
    short8 g8 = *(const short8*)(gio + gbase);
    short8 o8 = *(const short8*)(oLDS + osw(rowl, c8*2));
    short8 out;
    #pragma unroll
    for (int e=0;e<8;e++){
      float gv = bf2f((unsigned short)g8[e]);
      float sw = gv / (1.f + expf(-gv));
      out[e] = (short)f2bf(bf2f((unsigned short)o8[e]) * sw);
    }
    *(short8*)(gio + gbase) = out;
  }
  (void)dummy;
}

// ---------------- launch ----------------
extern "C" void kernel_launch(void* const* d_in, const int* in_sizes, int n_in,
                              void* d_out, int out_size, void* d_ws, size_t ws_size,
                              hipStream_t stream) {
  (void)in_sizes; (void)n_in; (void)out_size;
  const float* hs  = (const float*)d_in[0];
  const float* Wq  = (const float*)d_in[1];
  const float* Wk  = (const float*)d_in[2];
  const float* Wv  = (const float*)d_in[3];
  const float* Wa  = (const float*)d_in[4];
  const float* Wg  = (const float*)d_in[5];
  const float* Wo  = (const float*)d_in[6];
  const float* Al  = (const float*)d_in[7];
  const float* dtb = (const float*)d_in[8];
  const float* rmsw= (const float*)d_in[9];
  char* ws = (char*)d_ws;

  // workspace layout — total stays within known-safe 176,947,200 B
  constexpr size_t MB = 1048576;
  constexpr size_t OFF_Q    = 0;            // 16MB bf16 q
  constexpr size_t OFF_K    = 16*MB;        // 16MB bf16 k
  constexpr size_t OFF_V    = 32*MB;        // 32MB bf16 v
  constexpr size_t OFF_G    = 64*MB;        // 32MB bf16 gate -> o2 in-place
  constexpr size_t OFF_WQH  = 96*MB;        // 1MB
  constexpr size_t OFF_WQL  = 97*MB;        // 1MB
  constexpr size_t OFF_WKH  = 98*MB;        // 1MB
  constexpr size_t OFF_WKL  = 99*MB;        // 1MB
  constexpr size_t OFF_WV   = 100*MB;       // 2MB
  constexpr size_t OFF_WG   = 102*MB;       // 2MB
  constexpr size_t OFF_WO   = 104*MB;       // 2MB
  constexpr size_t OFF_GC   = 106*MB;                 // 256KB
  constexpr size_t OFF_GD   = 106*MB + 262144;        // 512KB
  constexpr size_t OFF_SBC  = 107*MB;       // 64MB bf16 chunk states; hsh/hsl alias here pre-phaseA
  constexpr size_t WS_REQUIRED = 176947200;
  if (ws_size < WS_REQUIRED) return;

  unsigned short* qb  = (unsigned short*)(ws + OFF_Q);
  unsigned short* kb  = (unsigned short*)(ws + OFF_K);
  unsigned short* vb  = (unsigned short*)(ws + OFF_V);
  unsigned short* gb  = (unsigned short*)(ws + OFF_G);
  unsigned short* wqh = (unsigned short*)(ws + OFF_WQH);
  unsigned short* wql = (unsigned short*)(ws + OFF_WQL);
  unsigned short* wkh = (unsigned short*)(ws + OFF_WKH);
  unsigned short* wkl = (unsigned short*)(ws + OFF_WKL);
  unsigned short* wvt = (unsigned short*)(ws + OFF_WV);
  unsigned short* wgt = (unsigned short*)(ws + OFF_WG);
  unsigned short* wot = (unsigned short*)(ws + OFF_WO);
  float* Gc   = (float*)(ws + OFF_GC);
  double* Gd  = (double*)(ws + OFF_GD);
  unsigned short* Sbc = (unsigned short*)(ws + OFF_SBC);
  unsigned short* hsh = (unsigned short*)(ws + OFF_SBC);          // 32MB, dead before phaseA
  unsigned short* hsl = (unsigned short*)(ws + OFF_SBC + 32*MB);  // 32MB, dead before phaseA

  // hs hi/lo split + weight transposes
  k_split<<<8192, 256, 0, stream>>>(hs, hsh, hsl, NB*NT*ND);
  k_tc2<<<2048, 256, 0, stream>>>(Wq, wqh, wql, 1024, 512);
  k_tc2<<<2048, 256, 0, stream>>>(Wk, wkh, wkl, 1024, 512);
  k_tc <<<4096, 256, 0, stream>>>(Wv, wvt, 1024, 1024);
  k_tc <<<4096, 256, 0, stream>>>(Wg, wgt, 1024, 1024);
  k_tc <<<4096, 256, 0, stream>>>(Wo, wot, 1024, 1024);

  // projections: q,k high-precision (A-split + B-split); v,g plain bf16 single-pass
  k_gemm2<1,1><<<dim3(128,4), 256, 0, stream>>>(hsh, hsl, wqh, wql, qb, 16384, 512, 1024);
  k_gemm2<1,1><<<dim3(128,4), 256, 0, stream>>>(hsh, hsl, wkh, wkl, kb, 16384, 512, 1024);
  k_gemm2<0,0><<<dim3(128,8), 256, 0, stream>>>(hsh, nullptr, wvt, nullptr, vb, 16384, 1024, 1024);
  k_gemm2<0,0><<<dim3(128,8), 256, 0, stream>>>(hsh, nullptr, wgt, nullptr, gb, 16384, 1024, 1024);

  k_alpha<<<16384, 256, 0, stream>>>(hs, Wa, Al, dtb, Gc);
  k_cumsum<<<8, 256, 0, stream>>>(Gc, Gd);

  k_phaseA<<<dim3(NCHK,8), 256, 0, stream>>>(kb, vb, Gd, Sbc);
  k_phaseB<<<dim3(32,8), 256, 0, stream>>>(Sbc, Gd);
  k_phaseC<<<dim3(NCHK,8), 256, 0, stream>>>(qb, kb, vb, gb, rmsw, Gd, Sbc, 0);

  // final GEMM: o2 (= gb region) @ Wo^T
  k_gemm<<<dim3(128,8), 256, 0, stream>>>(gb, wot, (float*)d_out, 16384, 1024, 1024);
}